// Round 12
// baseline (356.240 us; speedup 1.0000x reference)
//
#include <hip/hip_runtime.h>

#define B_DIM 32
#define C_DIM 64
#define F_DIM 16384
#define O_DIM 128
#define NBLK4 ((F_DIM / 128) * B_DIM)   // 4096 compute blocks (128 points each)

typedef __attribute__((ext_vector_type(8))) short short8;
typedef __attribute__((ext_vector_type(4))) float f32x4;

__device__ __forceinline__ ushort f2bf(float f) {
    union { float f; uint u; } v; v.f = f;
    return (ushort)((v.u + 0x7FFFu + ((v.u >> 16) & 1u)) >> 16);
}
__device__ __forceinline__ float bflo(uint u) {
    union { uint u; float f; } v; v.u = u << 16; return v.f;
}
__device__ __forceinline__ float bfhi(uint u) {
    union { uint u; float f; } v; v.u = u & 0xFFFF0000u; return v.f;
}
__device__ __forceinline__ uint beta_pair(uint tu, uint au, uint bu, uint cu) {
    const float tl = bflo(tu), th = bfhi(tu);
    const float lo = fabsf(tl - bflo(au)) + fabsf(tl - bflo(bu)) + fabsf(tl - bflo(cu));
    const float hi = fabsf(th - bfhi(au)) + fabsf(th - bfhi(bu)) + fabsf(th - bfhi(cu));
    return (uint)f2bf(lo) | ((uint)f2bf(hi) << 16);
}

// ------- Pass 1: transpose x (B,C,F) fp32 -> xt (B,F,C) bf16  (+W prep) -----
__global__ __launch_bounds__(256) void k_transpose(const float* __restrict__ x,
                                                   ushort* __restrict__ xt,
                                                   const float* __restrict__ W,
                                                   ushort* __restrict__ Wtg) {
    __shared__ float tile[64][65];
    const int b  = blockIdx.y;
    const int f0 = blockIdx.x * 64;
    const int t  = threadIdx.x;
    const int fl = t & 63;
    const int q  = t >> 6;

    const float* xb = x + (size_t)b * C_DIM * F_DIM;
    #pragma unroll
    for (int i = 0; i < 16; ++i) {
        const int c = q + i * 4;
        tile[c][fl] = __builtin_nontemporal_load(&xb[(size_t)c * F_DIM + f0 + fl]);
    }

    if (blockIdx.x == 0 && blockIdx.y == 0 && t < 128) {
        const int o = t;
        #pragma unroll 8
        for (int c = 0; c < C_DIM; ++c) {
            Wtg[o * 128 + c]      = f2bf(W[o * 128 + c * 2]);
            Wtg[o * 128 + 64 + c] = f2bf(W[o * 128 + c * 2 + 1]);
        }
    }

    __syncthreads();

    const int f  = t >> 2;
    const int ch = t & 3;
    union { ushort s[16]; uint4 v[2]; } u;
    #pragma unroll
    for (int j = 0; j < 16; ++j)
        u.s[j] = f2bf(tile[ch * 16 + j][f]);
    ushort* dst = xt + ((size_t)b * F_DIM + f0 + f) * C_DIM + ch * 16;
    *(uint4*)(dst)     = u.v[0];
    *(uint4*)(dst + 8) = u.v[1];
}

// ------------- Pass 2/4: gather + beta + MFMA GEMM ---------------------------
// 512 threads / 8 waves / 128-point A tile. W read directly from global
// (L1/L2-resident 32 KB) -- no Wsm LDS staging -> LDS 40 KB -> 3 blocks/CU.
// MODE 0: accumulate per-block (sum,sumsq) per o -> part, no y store.
// MODE 1: apply scale/shift (ss) + ReLU, store final y (nontemporal).
template <int MODE>
__global__ __launch_bounds__(512, 6) void k_compute_t(const ushort* __restrict__ xt,
                                                      const int*    __restrict__ adj,
                                                      const ushort* __restrict__ Wtg,
                                                      const float*  __restrict__ bias,
                                                      const float*  __restrict__ ss,
                                                      float*        __restrict__ y,
                                                      float*        __restrict__ part) {
    __shared__ __align__(16) char Asm[128 * 256];   // A tile: 128 rows x 128 bf16 (swizzled)

    const int bid = blockIdx.x;
    const int tg  = (bid & 7) * (NBLK4 / 8) + (bid >> 3);   // XCD-aware, bijective
    const int b   = tg >> 7;                                 // 128 tiles per batch
    const int f0  = (tg & 127) * 128;
    const int t   = threadIdx.x;

    // --- issue all 8 scattered gather loads FIRST (latency overlap) ---
    const int p  = t >> 2;          // point 0..127
    const int ch = t & 3;           // 32B c-chunk
    const int4 a4 = ((const int4*)adj)[(size_t)b * F_DIM + f0 + p];
    const char* xb = (const char*)(xt + (size_t)b * F_DIM * C_DIM);
    const char* r0 = xb + (size_t)a4.x * 128 + ch * 32;
    const char* r1 = xb + (size_t)a4.y * 128 + ch * 32;
    const char* r2 = xb + (size_t)a4.z * 128 + ch * 32;
    const char* r3 = xb + (size_t)a4.w * 128 + ch * 32;
    uint4 g[8];
    g[0] = *(const uint4*)(r0);  g[1] = *(const uint4*)(r0 + 16);
    g[2] = *(const uint4*)(r1);  g[3] = *(const uint4*)(r1 + 16);
    g[4] = *(const uint4*)(r2);  g[5] = *(const uint4*)(r2 + 16);
    g[6] = *(const uint4*)(r3);  g[7] = *(const uint4*)(r3 + 16);

    // --- beta + A-tile store (swizzled) ---
    {
        const int sw = (p & 7) << 4;
        char* Arow = Asm + p * 256;
        #pragma unroll
        for (int h = 0; h < 2; ++h) {
            const uint4 t0 = g[h], n1 = g[2 + h], n2 = g[4 + h], n3 = g[6 + h];
            *(uint4*)(Arow + ((ch * 32 + h * 16) ^ sw)) = t0;   // target bits
            const uint tu[4] = { t0.x, t0.y, t0.z, t0.w };
            const uint au[4] = { n1.x, n1.y, n1.z, n1.w };
            const uint bu[4] = { n2.x, n2.y, n2.z, n2.w };
            const uint cu[4] = { n3.x, n3.y, n3.z, n3.w };
            uint bt[4];
            #pragma unroll
            for (int qq = 0; qq < 4; ++qq)
                bt[qq] = beta_pair(tu[qq], au[qq], bu[qq], cu[qq]);
            *(uint4*)(Arow + ((128 + ch * 32 + h * 16) ^ sw)) =
                make_uint4(bt[0], bt[1], bt[2], bt[3]);
        }
    }

    __syncthreads();

    // --- MFMA: wave w (0..7) owns m-rows [w*16, w*16+16), all 128 o ---
    const int w     = t >> 6;
    const int l     = t & 63;
    const int col16 = l & 15;
    const int kg    = l >> 4;
    const int swl   = (l & 7) << 4;

    f32x4 acc[8];
    #pragma unroll
    for (int s = 0; s < 8; ++s) {
        const float bv = bias[s * 16 + col16];
        acc[s] = (f32x4){ bv, bv, bv, bv };
    }

    // B-fragments straight from global Wtg (row s*16+col16, bytes kk*64+kg*16)
    const char* Wlane = (const char*)Wtg + col16 * 256 + kg * 16;
    const char* ArowR = Asm + (w * 16 + col16) * 256;
    #pragma unroll
    for (int kk = 0; kk < 4; ++kk) {
        const int koff = kk * 64 + kg * 16;
        const short8 af = *(const short8*)(ArowR + (koff ^ swl));
        #pragma unroll
        for (int s = 0; s < 8; ++s) {
            const short8 bf = *(const short8*)(Wlane + s * 4096 + kk * 64);
            acc[s] = __builtin_amdgcn_mfma_f32_16x16x32_bf16(af, bf, acc[s], 0, 0, 0);
        }
    }

    if (MODE == 0) {
        // --- reduce acc -> per-block (sum,sumsq) per o, write partials ---
        __shared__ float sm_s[8][128];
        __shared__ float sm_q[8][128];
        #pragma unroll
        for (int s = 0; s < 8; ++s) {
            float ps = acc[s].x + acc[s].y + acc[s].z + acc[s].w;
            float pq = acc[s].x * acc[s].x + acc[s].y * acc[s].y
                     + acc[s].z * acc[s].z + acc[s].w * acc[s].w;
            ps += __shfl_xor(ps, 16, 64);  pq += __shfl_xor(pq, 16, 64);
            ps += __shfl_xor(ps, 32, 64);  pq += __shfl_xor(pq, 32, 64);
            if (kg == 0) {
                sm_s[w][s * 16 + col16] = ps;
                sm_q[w][s * 16 + col16] = pq;
            }
        }
        __syncthreads();
        if (t < 128) {
            float a = 0.f, c = 0.f;
            #pragma unroll
            for (int ww = 0; ww < 8; ++ww) { a += sm_s[ww][t]; c += sm_q[ww][t]; }
            part[(size_t)t * NBLK4 + bid]         = a;
            part[(size_t)(128 + t) * NBLK4 + bid] = c;
        }
    } else {
        // MODE 1: normalize + ReLU + coalesced nontemporal float4 stores
        const int fbase = f0 + w * 16 + kg * 4;
        #pragma unroll
        for (int s = 0; s < 8; ++s) {
            const int o = s * 16 + col16;
            const float sc = ss[o];
            const float sh = ss[O_DIM + o];
            f32x4 v = acc[s];
            v.x = fmaxf(fmaf(v.x, sc, sh), 0.f);
            v.y = fmaxf(fmaf(v.y, sc, sh), 0.f);
            v.z = fmaxf(fmaf(v.z, sc, sh), 0.f);
            v.w = fmaxf(fmaf(v.w, sc, sh), 0.f);
            __builtin_nontemporal_store(v, (f32x4*)(y + ((size_t)b * O_DIM + o) * F_DIM + fbase));
        }
    }
}

// ------------- Pass 3: reduce partials + finalize scale/shift ---------------
__global__ __launch_bounds__(256) void k_reduce_finalize(const float* __restrict__ part,
                                                         const float* __restrict__ gamma,
                                                         const float* __restrict__ beta_bn,
                                                         float* __restrict__ ss) {
    const int o = blockIdx.x;
    const int t = threadIdx.x;
    const float4* p1 = (const float4*)(part + (size_t)o * NBLK4);
    const float4* p2 = (const float4*)(part + (size_t)(128 + o) * NBLK4);
    float s = 0.f, q = 0.f;
    for (int i = t; i < NBLK4 / 4; i += 256) {
        const float4 v = p1[i];
        s += v.x + v.y + v.z + v.w;
        const float4 u = p2[i];
        q += u.x + u.y + u.z + u.w;
    }
    #pragma unroll
    for (int off = 32; off > 0; off >>= 1) {
        s += __shfl_down(s, off, 64);
        q += __shfl_down(q, off, 64);
    }
    __shared__ float ls[8];
    const int wid = t >> 6, lane = t & 63;
    if (lane == 0) { ls[wid] = s; ls[4 + wid] = q; }
    __syncthreads();
    if (t == 0) {
        const float ts = ls[0] + ls[1] + ls[2] + ls[3];
        const float tq = ls[4] + ls[5] + ls[6] + ls[7];
        const float n    = (float)B_DIM * (float)F_DIM;
        const float mean = ts / n;
        const float var  = tq / n - mean * mean;
        const float sc   = gamma[o] * rsqrtf(var + 1e-5f);
        ss[o]         = sc;
        ss[O_DIM + o] = beta_bn[o] - mean * sc;
    }
}

// ================== fallback path (small ws) — round-1 known-correct ========
__global__ __launch_bounds__(256) void k_compute_slow(const float* __restrict__ xsrc,
                                                      const int*   __restrict__ adj,
                                                      const float* __restrict__ W,
                                                      const float* __restrict__ bias,
                                                      float*       __restrict__ y) {
    const int b = blockIdx.y;
    const int f = blockIdx.x * 256 + threadIdx.x;
    const int4 a = ((const int4*)adj)[(size_t)b * F_DIM + f];
    float tg[64], bt[64];
    const float* base = xsrc + (size_t)b * C_DIM * F_DIM;
    #pragma unroll
    for (int c = 0; c < 64; ++c) {
        const float tv = base[(size_t)c * F_DIM + a.x];
        const float n1 = base[(size_t)c * F_DIM + a.y];
        const float n2 = base[(size_t)c * F_DIM + a.z];
        const float n3 = base[(size_t)c * F_DIM + a.w];
        tg[c] = tv;
        bt[c] = fabsf(tv - n1) + fabsf(tv - n2) + fabsf(tv - n3);
    }
    float* yb = y + (size_t)b * O_DIM * F_DIM + f;
    const float2* W2 = (const float2*)W;
    #pragma unroll 4
    for (int o = 0; o < O_DIM; ++o) {
        float acc = bias[o];
        #pragma unroll
        for (int c = 0; c < 64; ++c) {
            const float2 wv = W2[o * 64 + c];
            acc = fmaf(tg[c], wv.x, fmaf(bt[c], wv.y, acc));
        }
        yb[(size_t)o * F_DIM] = acc;
    }
}

__global__ __launch_bounds__(256) void k_stats(const float* __restrict__ y,
                                               float* __restrict__ stats) {
    const int o = blockIdx.x;
    const int b = blockIdx.y;
    const float4* row = (const float4*)(y + ((size_t)b * O_DIM + o) * F_DIM);
    float s = 0.f, s2 = 0.f;
    for (int i = threadIdx.x; i < F_DIM / 4; i += 256) {
        const float4 v = row[i];
        s  += v.x + v.y + v.z + v.w;
        s2 += v.x * v.x + v.y * v.y + v.z * v.z + v.w * v.w;
    }
    #pragma unroll
    for (int off = 32; off > 0; off >>= 1) {
        s  += __shfl_down(s,  off, 64);
        s2 += __shfl_down(s2, off, 64);
    }
    __shared__ float ls[4], ls2[4];
    const int wid = threadIdx.x >> 6, lane = threadIdx.x & 63;
    if (lane == 0) { ls[wid] = s; ls2[wid] = s2; }
    __syncthreads();
    if (threadIdx.x == 0) {
        atomicAdd(&stats[o],         ls[0] + ls[1] + ls[2] + ls[3]);
        atomicAdd(&stats[O_DIM + o], ls2[0] + ls2[1] + ls2[2] + ls2[3]);
    }
}

__global__ void k_finalize(const float* __restrict__ stats,
                           const float* __restrict__ gamma,
                           const float* __restrict__ beta_bn,
                           float* __restrict__ ss) {
    const int o = threadIdx.x;
    if (o < O_DIM) {
        const float n    = (float)B_DIM * (float)F_DIM;
        const float mean = stats[o] / n;
        const float var  = stats[O_DIM + o] / n - mean * mean;
        const float sc   = gamma[o] * rsqrtf(var + 1e-5f);
        ss[o]         = sc;
        ss[O_DIM + o] = beta_bn[o] - mean * sc;
    }
}

__global__ __launch_bounds__(256) void k_norm(float* __restrict__ y,
                                              const float* __restrict__ ss) {
    const size_t n4 = (size_t)B_DIM * O_DIM * F_DIM / 4;
    const size_t stride = (size_t)gridDim.x * blockDim.x;
    float4* y4 = (float4*)y;
    for (size_t i = (size_t)blockIdx.x * blockDim.x + threadIdx.x; i < n4; i += stride) {
        const int o = (int)((i >> 12) & (O_DIM - 1));
        const float sc = ss[o];
        const float sh = ss[O_DIM + o];
        float4 v = y4[i];
        v.x = fmaxf(fmaf(v.x, sc, sh), 0.f);
        v.y = fmaxf(fmaf(v.y, sc, sh), 0.f);
        v.z = fmaxf(fmaf(v.z, sc, sh), 0.f);
        v.w = fmaxf(fmaf(v.w, sc, sh), 0.f);
        y4[i] = v;
    }
}

extern "C" void kernel_launch(void* const* d_in, const int* in_sizes, int n_in,
                              void* d_out, int out_size, void* d_ws, size_t ws_size,
                              hipStream_t stream) {
    const float* x       = (const float*)d_in[0];
    const int*   adj     = (const int*)  d_in[1];
    const float* W       = (const float*)d_in[2];
    const float* bias    = (const float*)d_in[3];
    const float* gamma   = (const float*)d_in[4];
    const float* beta_bn = (const float*)d_in[5];
    float* out = (float*)d_out;

    const size_t XT_B   = (size_t)B_DIM * F_DIM * C_DIM * 2;            // 64 MB
    const size_t PART_B = (size_t)2 * O_DIM * NBLK4 * sizeof(float);    // 4 MB

    float*  stats = (float*)d_ws;
    float*  ss    = (float*)((char*)d_ws + 1024);
    ushort* Wtg   = (ushort*)((char*)d_ws + 4096);
    ushort* xt    = (ushort*)((char*)d_ws + 65536);
    float*  part  = (float*)((char*)d_ws + 65536 + XT_B);

    const size_t need = 65536 + XT_B + PART_B;

    if (ws_size >= need) {
        k_transpose<<<dim3(F_DIM / 64, B_DIM), 256, 0, stream>>>(x, xt, W, Wtg);
        k_compute_t<0><<<dim3(NBLK4), 512, 0, stream>>>(xt, adj, Wtg, bias, nullptr, nullptr, part);
        k_reduce_finalize<<<O_DIM, 256, 0, stream>>>(part, gamma, beta_bn, ss);
        k_compute_t<1><<<dim3(NBLK4), 512, 0, stream>>>(xt, adj, Wtg, bias, ss, out, nullptr);
    } else {
        hipMemsetAsync(stats, 0, 2 * O_DIM * sizeof(float), stream);
        k_compute_slow<<<dim3(F_DIM / 256, B_DIM), 256, 0, stream>>>(x, adj, W, bias, out);
        k_stats<<<dim3(O_DIM, B_DIM), 256, 0, stream>>>(out, stats);
        k_finalize<<<1, 128, 0, stream>>>(stats, gamma, beta_bn, ss);
        k_norm<<<2048, 256, 0, stream>>>(out, ss);
    }
}

// Round 13
// 320.940 us; speedup vs baseline: 1.1100x; 1.1100x over previous
//
#include <hip/hip_runtime.h>

#define B_DIM 32
#define C_DIM 64
#define F_DIM 16384
#define O_DIM 128
#define NBLK4 ((F_DIM / 128) * B_DIM)   // 4096 compute blocks (128 points each)

typedef __attribute__((ext_vector_type(8))) short short8;
typedef __attribute__((ext_vector_type(4))) float f32x4;

__device__ __forceinline__ ushort f2bf(float f) {
    union { float f; uint u; } v; v.f = f;
    return (ushort)((v.u + 0x7FFFu + ((v.u >> 16) & 1u)) >> 16);
}
__device__ __forceinline__ float bflo(uint u) {
    union { uint u; float f; } v; v.u = u << 16; return v.f;
}
__device__ __forceinline__ float bfhi(uint u) {
    union { uint u; float f; } v; v.u = u & 0xFFFF0000u; return v.f;
}
__device__ __forceinline__ uint beta_pair(uint tu, uint au, uint bu, uint cu) {
    const float tl = bflo(tu), th = bfhi(tu);
    const float lo = fabsf(tl - bflo(au)) + fabsf(tl - bflo(bu)) + fabsf(tl - bflo(cu));
    const float hi = fabsf(th - bfhi(au)) + fabsf(th - bfhi(bu)) + fabsf(th - bfhi(cu));
    return (uint)f2bf(lo) | ((uint)f2bf(hi) << 16);
}

// ------- Pass 1: transpose x (B,C,F) fp32 -> xt (B,F,C) bf16  (+W prep) -----
__global__ __launch_bounds__(256) void k_transpose(const float* __restrict__ x,
                                                   ushort* __restrict__ xt,
                                                   const float* __restrict__ W,
                                                   ushort* __restrict__ Wtg) {
    __shared__ float tile[64][65];
    const int b  = blockIdx.y;
    const int f0 = blockIdx.x * 64;
    const int t  = threadIdx.x;
    const int fl = t & 63;
    const int q  = t >> 6;

    const float* xb = x + (size_t)b * C_DIM * F_DIM;
    #pragma unroll
    for (int i = 0; i < 16; ++i) {
        const int c = q + i * 4;
        tile[c][fl] = __builtin_nontemporal_load(&xb[(size_t)c * F_DIM + f0 + fl]);
    }

    if (blockIdx.x == 0 && blockIdx.y == 0 && t < 128) {
        const int o = t;
        #pragma unroll 8
        for (int c = 0; c < C_DIM; ++c) {
            Wtg[o * 128 + c]      = f2bf(W[o * 128 + c * 2]);
            Wtg[o * 128 + 64 + c] = f2bf(W[o * 128 + c * 2 + 1]);
        }
    }

    __syncthreads();

    const int f  = t >> 2;
    const int ch = t & 3;
    union { ushort s[16]; uint4 v[2]; } u;
    #pragma unroll
    for (int j = 0; j < 16; ++j)
        u.s[j] = f2bf(tile[ch * 16 + j][f]);
    ushort* dst = xt + ((size_t)b * F_DIM + f0 + f) * C_DIM + ch * 16;
    *(uint4*)(dst)     = u.v[0];
    *(uint4*)(dst + 8) = u.v[1];
}

// ------------- Pass 2/4: gather + beta + MFMA GEMM ---------------------------
// 512 threads / 8 waves / 128-point A tile. Two sequential o-half-passes with
// acc[4] (16 VGPR) instead of acc[8]; W read directly from global (32 KB,
// L1/L2-resident); LDS <= 40 KB. __launch_bounds__(512,8) -> VGPR cap 64 ->
// target 8 waves/SIMD (2x round-11 occupancy).
// MODE 0: accumulate per-block (sum,sumsq) per o -> part, no y store.
// MODE 1: apply scale/shift (ss) + ReLU, store final y (nontemporal).
template <int MODE>
__global__ __launch_bounds__(512, 8) void k_compute_t(const ushort* __restrict__ xt,
                                                      const int*    __restrict__ adj,
                                                      const ushort* __restrict__ Wtg,
                                                      const float*  __restrict__ bias,
                                                      const float*  __restrict__ ss,
                                                      float*        __restrict__ y,
                                                      float*        __restrict__ part) {
    __shared__ __align__(16) char Asm[128 * 256];   // A tile: 128 rows x 128 bf16 (swizzled)
    __shared__ float sm_s[MODE == 0 ? 8 : 1][128];  // MODE0 only (8 KB)
    __shared__ float sm_q[MODE == 0 ? 8 : 1][128];

    const int bid = blockIdx.x;
    const int tg  = (bid & 7) * (NBLK4 / 8) + (bid >> 3);   // XCD-aware, bijective
    const int b   = tg >> 7;                                 // 128 tiles per batch
    const int f0  = (tg & 127) * 128;
    const int t   = threadIdx.x;

    // --- issue all 8 scattered gather loads FIRST (latency overlap) ---
    const int p  = t >> 2;          // point 0..127
    const int ch = t & 3;           // 32B c-chunk
    const int4 a4 = ((const int4*)adj)[(size_t)b * F_DIM + f0 + p];
    const char* xb = (const char*)(xt + (size_t)b * F_DIM * C_DIM);
    const char* r0 = xb + (size_t)a4.x * 128 + ch * 32;
    const char* r1 = xb + (size_t)a4.y * 128 + ch * 32;
    const char* r2 = xb + (size_t)a4.z * 128 + ch * 32;
    const char* r3 = xb + (size_t)a4.w * 128 + ch * 32;
    uint4 g[8];
    g[0] = *(const uint4*)(r0);  g[1] = *(const uint4*)(r0 + 16);
    g[2] = *(const uint4*)(r1);  g[3] = *(const uint4*)(r1 + 16);
    g[4] = *(const uint4*)(r2);  g[5] = *(const uint4*)(r2 + 16);
    g[6] = *(const uint4*)(r3);  g[7] = *(const uint4*)(r3 + 16);

    // --- beta + A-tile store (swizzled) ---
    {
        const int sw = (p & 7) << 4;
        char* Arow = Asm + p * 256;
        #pragma unroll
        for (int h = 0; h < 2; ++h) {
            const uint4 t0 = g[h], n1 = g[2 + h], n2 = g[4 + h], n3 = g[6 + h];
            *(uint4*)(Arow + ((ch * 32 + h * 16) ^ sw)) = t0;   // target bits
            const uint tu[4] = { t0.x, t0.y, t0.z, t0.w };
            const uint au[4] = { n1.x, n1.y, n1.z, n1.w };
            const uint bu[4] = { n2.x, n2.y, n2.z, n2.w };
            const uint cu[4] = { n3.x, n3.y, n3.z, n3.w };
            uint bt[4];
            #pragma unroll
            for (int qq = 0; qq < 4; ++qq)
                bt[qq] = beta_pair(tu[qq], au[qq], bu[qq], cu[qq]);
            *(uint4*)(Arow + ((128 + ch * 32 + h * 16) ^ sw)) =
                make_uint4(bt[0], bt[1], bt[2], bt[3]);
        }
    }

    __syncthreads();

    // --- MFMA: wave w (0..7) owns m-rows [w*16,w*16+16); o in 2 half-passes ---
    const int w     = t >> 6;
    const int l     = t & 63;
    const int col16 = l & 15;
    const int kg    = l >> 4;
    const int swl   = (l & 7) << 4;
    const char* ArowR = Asm + (w * 16 + col16) * 256;
    // B base for this lane: row col16 (+ s*16 + half*64), k-chunk kg*16
    const char* Wlane = (const char*)Wtg + col16 * 256 + kg * 16;

    #pragma unroll
    for (int half = 0; half < 2; ++half) {
        f32x4 acc[4];
        #pragma unroll
        for (int s = 0; s < 4; ++s) {
            const float bv = bias[half * 64 + s * 16 + col16];
            acc[s] = (f32x4){ bv, bv, bv, bv };
        }
        #pragma unroll
        for (int kk = 0; kk < 4; ++kk) {
            const short8 af = *(const short8*)(ArowR + ((kk * 64 + kg * 16) ^ swl));
            #pragma unroll
            for (int s = 0; s < 4; ++s) {
                const short8 bf = *(const short8*)(Wlane + (half * 64 + s * 16) * 256 + kk * 64);
                acc[s] = __builtin_amdgcn_mfma_f32_16x16x32_bf16(af, bf, acc[s], 0, 0, 0);
            }
        }

        if (MODE == 0) {
            #pragma unroll
            for (int s = 0; s < 4; ++s) {
                float ps = acc[s].x + acc[s].y + acc[s].z + acc[s].w;
                float pq = acc[s].x * acc[s].x + acc[s].y * acc[s].y
                         + acc[s].z * acc[s].z + acc[s].w * acc[s].w;
                ps += __shfl_xor(ps, 16, 64);  pq += __shfl_xor(pq, 16, 64);
                ps += __shfl_xor(ps, 32, 64);  pq += __shfl_xor(pq, 32, 64);
                if (kg == 0) {
                    sm_s[w][half * 64 + s * 16 + col16] = ps;
                    sm_q[w][half * 64 + s * 16 + col16] = pq;
                }
            }
        } else {
            const int fbase = f0 + w * 16 + kg * 4;
            #pragma unroll
            for (int s = 0; s < 4; ++s) {
                const int o = half * 64 + s * 16 + col16;
                const float sc = ss[o];
                const float sh = ss[O_DIM + o];
                f32x4 v = acc[s];
                v.x = fmaxf(fmaf(v.x, sc, sh), 0.f);
                v.y = fmaxf(fmaf(v.y, sc, sh), 0.f);
                v.z = fmaxf(fmaf(v.z, sc, sh), 0.f);
                v.w = fmaxf(fmaf(v.w, sc, sh), 0.f);
                __builtin_nontemporal_store(v, (f32x4*)(y + ((size_t)b * O_DIM + o) * F_DIM + fbase));
            }
        }
    }

    if (MODE == 0) {
        __syncthreads();
        if (t < 128) {
            float a = 0.f, c = 0.f;
            #pragma unroll
            for (int ww = 0; ww < 8; ++ww) { a += sm_s[ww][t]; c += sm_q[ww][t]; }
            part[(size_t)t * NBLK4 + bid]         = a;
            part[(size_t)(128 + t) * NBLK4 + bid] = c;
        }
    }
}

// ------------- Pass 3: reduce partials + finalize scale/shift ---------------
__global__ __launch_bounds__(256) void k_reduce_finalize(const float* __restrict__ part,
                                                         const float* __restrict__ gamma,
                                                         const float* __restrict__ beta_bn,
                                                         float* __restrict__ ss) {
    const int o = blockIdx.x;
    const int t = threadIdx.x;
    const float4* p1 = (const float4*)(part + (size_t)o * NBLK4);
    const float4* p2 = (const float4*)(part + (size_t)(128 + o) * NBLK4);
    float s = 0.f, q = 0.f;
    for (int i = t; i < NBLK4 / 4; i += 256) {
        const float4 v = p1[i];
        s += v.x + v.y + v.z + v.w;
        const float4 u = p2[i];
        q += u.x + u.y + u.z + u.w;
    }
    #pragma unroll
    for (int off = 32; off > 0; off >>= 1) {
        s += __shfl_down(s, off, 64);
        q += __shfl_down(q, off, 64);
    }
    __shared__ float ls[8];
    const int wid = t >> 6, lane = t & 63;
    if (lane == 0) { ls[wid] = s; ls[4 + wid] = q; }
    __syncthreads();
    if (t == 0) {
        const float ts = ls[0] + ls[1] + ls[2] + ls[3];
        const float tq = ls[4] + ls[5] + ls[6] + ls[7];
        const float n    = (float)B_DIM * (float)F_DIM;
        const float mean = ts / n;
        const float var  = tq / n - mean * mean;
        const float sc   = gamma[o] * rsqrtf(var + 1e-5f);
        ss[o]         = sc;
        ss[O_DIM + o] = beta_bn[o] - mean * sc;
    }
}

// ================== fallback path (small ws) — round-1 known-correct ========
__global__ __launch_bounds__(256) void k_compute_slow(const float* __restrict__ xsrc,
                                                      const int*   __restrict__ adj,
                                                      const float* __restrict__ W,
                                                      const float* __restrict__ bias,
                                                      float*       __restrict__ y) {
    const int b = blockIdx.y;
    const int f = blockIdx.x * 256 + threadIdx.x;
    const int4 a = ((const int4*)adj)[(size_t)b * F_DIM + f];
    float tg[64], bt[64];
    const float* base = xsrc + (size_t)b * C_DIM * F_DIM;
    #pragma unroll
    for (int c = 0; c < 64; ++c) {
        const float tv = base[(size_t)c * F_DIM + a.x];
        const float n1 = base[(size_t)c * F_DIM + a.y];
        const float n2 = base[(size_t)c * F_DIM + a.z];
        const float n3 = base[(size_t)c * F_DIM + a.w];
        tg[c] = tv;
        bt[c] = fabsf(tv - n1) + fabsf(tv - n2) + fabsf(tv - n3);
    }
    float* yb = y + (size_t)b * O_DIM * F_DIM + f;
    const float2* W2 = (const float2*)W;
    #pragma unroll 4
    for (int o = 0; o < O_DIM; ++o) {
        float acc = bias[o];
        #pragma unroll
        for (int c = 0; c < 64; ++c) {
            const float2 wv = W2[o * 64 + c];
            acc = fmaf(tg[c], wv.x, fmaf(bt[c], wv.y, acc));
        }
        yb[(size_t)o * F_DIM] = acc;
    }
}

__global__ __launch_bounds__(256) void k_stats(const float* __restrict__ y,
                                               float* __restrict__ stats) {
    const int o = blockIdx.x;
    const int b = blockIdx.y;
    const float4* row = (const float4*)(y + ((size_t)b * O_DIM + o) * F_DIM);
    float s = 0.f, s2 = 0.f;
    for (int i = threadIdx.x; i < F_DIM / 4; i += 256) {
        const float4 v = row[i];
        s  += v.x + v.y + v.z + v.w;
        s2 += v.x * v.x + v.y * v.y + v.z * v.z + v.w * v.w;
    }
    #pragma unroll
    for (int off = 32; off > 0; off >>= 1) {
        s  += __shfl_down(s,  off, 64);
        s2 += __shfl_down(s2, off, 64);
    }
    __shared__ float ls[4], ls2[4];
    const int wid = threadIdx.x >> 6, lane = threadIdx.x & 63;
    if (lane == 0) { ls[wid] = s; ls2[wid] = s2; }
    __syncthreads();
    if (threadIdx.x == 0) {
        atomicAdd(&stats[o],         ls[0] + ls[1] + ls[2] + ls[3]);
        atomicAdd(&stats[O_DIM + o], ls2[0] + ls2[1] + ls2[2] + ls2[3]);
    }
}

__global__ void k_finalize(const float* __restrict__ stats,
                           const float* __restrict__ gamma,
                           const float* __restrict__ beta_bn,
                           float* __restrict__ ss) {
    const int o = threadIdx.x;
    if (o < O_DIM) {
        const float n    = (float)B_DIM * (float)F_DIM;
        const float mean = stats[o] / n;
        const float var  = stats[O_DIM + o] / n - mean * mean;
        const float sc   = gamma[o] * rsqrtf(var + 1e-5f);
        ss[o]         = sc;
        ss[O_DIM + o] = beta_bn[o] - mean * sc;
    }
}

__global__ __launch_bounds__(256) void k_norm(float* __restrict__ y,
                                              const float* __restrict__ ss) {
    const size_t n4 = (size_t)B_DIM * O_DIM * F_DIM / 4;
    const size_t stride = (size_t)gridDim.x * blockDim.x;
    float4* y4 = (float4*)y;
    for (size_t i = (size_t)blockIdx.x * blockDim.x + threadIdx.x; i < n4; i += stride) {
        const int o = (int)((i >> 12) & (O_DIM - 1));
        const float sc = ss[o];
        const float sh = ss[O_DIM + o];
        float4 v = y4[i];
        v.x = fmaxf(fmaf(v.x, sc, sh), 0.f);
        v.y = fmaxf(fmaf(v.y, sc, sh), 0.f);
        v.z = fmaxf(fmaf(v.z, sc, sh), 0.f);
        v.w = fmaxf(fmaf(v.w, sc, sh), 0.f);
        y4[i] = v;
    }
}

extern "C" void kernel_launch(void* const* d_in, const int* in_sizes, int n_in,
                              void* d_out, int out_size, void* d_ws, size_t ws_size,
                              hipStream_t stream) {
    const float* x       = (const float*)d_in[0];
    const int*   adj     = (const int*)  d_in[1];
    const float* W       = (const float*)d_in[2];
    const float* bias    = (const float*)d_in[3];
    const float* gamma   = (const float*)d_in[4];
    const float* beta_bn = (const float*)d_in[5];
    float* out = (float*)d_out;

    const size_t XT_B   = (size_t)B_DIM * F_DIM * C_DIM * 2;            // 64 MB
    const size_t PART_B = (size_t)2 * O_DIM * NBLK4 * sizeof(float);    // 4 MB

    float*  stats = (float*)d_ws;
    float*  ss    = (float*)((char*)d_ws + 1024);
    ushort* Wtg   = (ushort*)((char*)d_ws + 4096);
    ushort* xt    = (ushort*)((char*)d_ws + 65536);
    float*  part  = (float*)((char*)d_ws + 65536 + XT_B);

    const size_t need = 65536 + XT_B + PART_B;

    if (ws_size >= need) {
        k_transpose<<<dim3(F_DIM / 64, B_DIM), 256, 0, stream>>>(x, xt, W, Wtg);
        k_compute_t<0><<<dim3(NBLK4), 512, 0, stream>>>(xt, adj, Wtg, bias, nullptr, nullptr, part);
        k_reduce_finalize<<<O_DIM, 256, 0, stream>>>(part, gamma, beta_bn, ss);
        k_compute_t<1><<<dim3(NBLK4), 512, 0, stream>>>(xt, adj, Wtg, bias, ss, out, nullptr);
    } else {
        hipMemsetAsync(stats, 0, 2 * O_DIM * sizeof(float), stream);
        k_compute_slow<<<dim3(F_DIM / 256, B_DIM), 256, 0, stream>>>(x, adj, W, bias, out);
        k_stats<<<dim3(O_DIM, B_DIM), 256, 0, stream>>>(out, stats);
        k_finalize<<<1, 128, 0, stream>>>(stats, gamma, beta_bn, ss);
        k_norm<<<2048, 256, 0, stream>>>(out, ss);
    }
}

// Round 14
// 200.906 us; speedup vs baseline: 1.7732x; 1.5975x over previous
//
#include <hip/hip_runtime.h>

#define B_DIM 32
#define C_DIM 64
#define F_DIM 16384
#define O_DIM 128
#define PBLK  512     // pipelined compute blocks
#define ITERS 16      // 64-pt tiles per block; 512*16*64 = 524288 points

typedef __attribute__((ext_vector_type(8))) short short8;
typedef __attribute__((ext_vector_type(4))) float f32x4;

__device__ __forceinline__ ushort f2bf(float f) {
    union { float f; uint u; } v; v.f = f;
    return (ushort)((v.u + 0x7FFFu + ((v.u >> 16) & 1u)) >> 16);
}
__device__ __forceinline__ float bflo(uint u) {
    union { uint u; float f; } v; v.u = u << 16; return v.f;
}
__device__ __forceinline__ float bfhi(uint u) {
    union { uint u; float f; } v; v.u = u & 0xFFFF0000u; return v.f;
}
__device__ __forceinline__ uint beta_pair(uint tu, uint au, uint bu, uint cu) {
    const float tl = bflo(tu), th = bfhi(tu);
    const float lo = fabsf(tl - bflo(au)) + fabsf(tl - bflo(bu)) + fabsf(tl - bflo(cu));
    const float hi = fabsf(th - bfhi(au)) + fabsf(th - bfhi(bu)) + fabsf(th - bfhi(cu));
    return (uint)f2bf(lo) | ((uint)f2bf(hi) << 16);
}

// ------- Pass 1: transpose x (B,C,F) fp32 -> xt (B,F,C) bf16  (+W prep) -----
__global__ __launch_bounds__(256) void k_transpose(const float* __restrict__ x,
                                                   ushort* __restrict__ xt,
                                                   const float* __restrict__ W,
                                                   ushort* __restrict__ Wtg) {
    __shared__ float tile[64][65];
    const int b  = blockIdx.y;
    const int f0 = blockIdx.x * 64;
    const int t  = threadIdx.x;
    const int fl = t & 63;
    const int q  = t >> 6;

    const float* xb = x + (size_t)b * C_DIM * F_DIM;
    #pragma unroll
    for (int i = 0; i < 16; ++i) {
        const int c = q + i * 4;
        tile[c][fl] = __builtin_nontemporal_load(&xb[(size_t)c * F_DIM + f0 + fl]);
    }

    if (blockIdx.x == 0 && blockIdx.y == 0 && t < 128) {
        const int o = t;
        #pragma unroll 8
        for (int c = 0; c < C_DIM; ++c) {
            Wtg[o * 128 + c]      = f2bf(W[o * 128 + c * 2]);
            Wtg[o * 128 + 64 + c] = f2bf(W[o * 128 + c * 2 + 1]);
        }
    }

    __syncthreads();

    const int f  = t >> 2;
    const int ch = t & 3;
    union { ushort s[16]; uint4 v[2]; } u;
    #pragma unroll
    for (int j = 0; j < 16; ++j)
        u.s[j] = f2bf(tile[ch * 16 + j][f]);
    ushort* dst = xt + ((size_t)b * F_DIM + f0 + f) * C_DIM + ch * 16;
    *(uint4*)(dst)     = u.v[0];
    *(uint4*)(dst + 8) = u.v[1];
}

// ---------- Pass 2/4: PIPELINED gather + beta + MFMA (16 x 64-pt tiles) -----
// One barrier per tile; double-buffered A in LDS; NO per-lane register state
// crosses any barrier (spill triggers from r5/r10/r12/r13 eliminated).
// Per iter: adjload(i+1) | MFMA(buf[i],kk01) | gathers(i+1) | MFMA(kk23) |
//           epilogue | WRITE_A(buf[i^1]) | barrier.
// MODE 0: per-wave (sum,sumsq) accumulated in LDS slots -> part.
// MODE 1: scale/shift + ReLU, nontemporal stores.
template <int MODE>
__global__ __launch_bounds__(512, 4) void k_pipe(const ushort* __restrict__ xt,
                                                 const int*    __restrict__ adj,
                                                 const ushort* __restrict__ Wtg,
                                                 const float*  __restrict__ bias,
                                                 const float*  __restrict__ ss,
                                                 float*        __restrict__ y,
                                                 float*        __restrict__ part) {
    __shared__ __align__(16) char A2[2][64 * 256];          // 2 x 16 KB
    __shared__ __align__(16) char Wsm[128 * 256];           // 32 KB
    __shared__ float sm_s[MODE == 0 ? 8 : 1][64];           // 4 KB (MODE0)
    __shared__ float sm_q[MODE == 0 ? 8 : 1][64];

    const int bid = blockIdx.x;
    const int xcd = bid & 7;
    const int j   = bid >> 3;                 // 0..63
    const int b   = xcd + 8 * (j >> 4);       // batch
    const int T0  = (j & 15) * 16;            // first 64-pt tile (256 per batch)
    const int t   = threadIdx.x;

    const int p   = t >> 3;                   // point row 0..63
    const int sub = t & 7;                    // 16B chunk 0..7
    const int swp = (p & 7) << 4;
    const int4* adjp = (const int4*)adj + (size_t)b * F_DIM;
    const char* xb   = (const char*)(xt + (size_t)b * F_DIM * C_DIM);

    const int w     = t >> 6;                 // wave 0..7
    const int l     = t & 63;
    const int col16 = l & 15;
    const int kg    = l >> 4;
    const int swl   = (col16 & 7) << 4;
    const int oh    = (w >> 2) * 64;          // o-half this wave owns
    const int mr    = (w & 3) * 16;           // m-row base within tile

    if (MODE == 0) {                          // zero 8x64 accum slots (512 thr)
        sm_s[t >> 6][t & 63] = 0.f;
        sm_q[t >> 6][t & 63] = 0.f;
    }

    // ---------------- prologue: tile T0 into buf0 ----------------
    {
        const int4 a4 = adjp[T0 * 64 + p];
        const uint4 g0 = *(const uint4*)(xb + (size_t)a4.x * 128 + sub * 16);
        const uint4 g1 = *(const uint4*)(xb + (size_t)a4.y * 128 + sub * 16);
        const uint4 g2 = *(const uint4*)(xb + (size_t)a4.z * 128 + sub * 16);
        const uint4 g3 = *(const uint4*)(xb + (size_t)a4.w * 128 + sub * 16);

        // stage W once (overlaps gather latency)
        const uint4* src = (const uint4*)Wtg;
        #pragma unroll
        for (int jj = 0; jj < 4; ++jj) {
            const int fb    = t * 64 + jj * 16;
            const int o     = fb >> 8;
            const int inner = fb & 255;
            *(uint4*)(Wsm + (o << 8) + (inner ^ ((o & 7) << 4))) = src[fb >> 4];
        }

        char* Arow = A2[0] + p * 256;
        *(uint4*)(Arow + ((sub * 16) ^ swp)) = g0;
        *(uint4*)(Arow + ((128 + sub * 16) ^ swp)) =
            make_uint4(beta_pair(g0.x, g1.x, g2.x, g3.x),
                       beta_pair(g0.y, g1.y, g2.y, g3.y),
                       beta_pair(g0.z, g1.z, g2.z, g3.z),
                       beta_pair(g0.w, g1.w, g2.w, g3.w));
    }
    __syncthreads();

    // ---------------- pipelined tile loop ----------------
    #pragma unroll
    for (int i = 0; i < ITERS; ++i) {
        const int cur = i & 1;
        const char* Ab   = A2[cur];
        const char* ArowR = Ab + (mr + col16) * 256;

        int4 an;
        if (i < ITERS - 1) an = adjp[(T0 + i + 1) * 64 + p];   // in flight

        f32x4 acc[4];
        #pragma unroll
        for (int s = 0; s < 4; ++s) {
            const float bv = bias[oh + s * 16 + col16];
            acc[s] = (f32x4){ bv, bv, bv, bv };
        }

        // MFMA half 1 (kk = 0,1) — covers adj latency
        #pragma unroll
        for (int kk = 0; kk < 2; ++kk) {
            const short8 af = *(const short8*)(ArowR + ((kk * 64 + kg * 16) ^ swl));
            #pragma unroll
            for (int s = 0; s < 4; ++s) {
                const short8 bf = *(const short8*)(Wsm + (oh + s * 16 + col16) * 256
                                                   + ((kk * 64 + kg * 16) ^ swl));
                acc[s] = __builtin_amdgcn_mfma_f32_16x16x32_bf16(af, bf, acc[s], 0, 0, 0);
            }
        }

        // issue next tile's gathers — covered by MFMA half 2 + epilogue
        uint4 g0, g1, g2, g3;
        if (i < ITERS - 1) {
            g0 = *(const uint4*)(xb + (size_t)an.x * 128 + sub * 16);
            g1 = *(const uint4*)(xb + (size_t)an.y * 128 + sub * 16);
            g2 = *(const uint4*)(xb + (size_t)an.z * 128 + sub * 16);
            g3 = *(const uint4*)(xb + (size_t)an.w * 128 + sub * 16);
        }

        // MFMA half 2 (kk = 2,3)
        #pragma unroll
        for (int kk = 2; kk < 4; ++kk) {
            const short8 af = *(const short8*)(ArowR + ((kk * 64 + kg * 16) ^ swl));
            #pragma unroll
            for (int s = 0; s < 4; ++s) {
                const short8 bf = *(const short8*)(Wsm + (oh + s * 16 + col16) * 256
                                                   + ((kk * 64 + kg * 16) ^ swl));
                acc[s] = __builtin_amdgcn_mfma_f32_16x16x32_bf16(af, bf, acc[s], 0, 0, 0);
            }
        }

        // epilogue
        if (MODE == 0) {
            #pragma unroll
            for (int s = 0; s < 4; ++s) {
                float ps = acc[s].x + acc[s].y + acc[s].z + acc[s].w;
                float pq = acc[s].x * acc[s].x + acc[s].y * acc[s].y
                         + acc[s].z * acc[s].z + acc[s].w * acc[s].w;
                ps += __shfl_xor(ps, 16, 64);  pq += __shfl_xor(pq, 16, 64);
                ps += __shfl_xor(ps, 32, 64);  pq += __shfl_xor(pq, 32, 64);
                if (kg == 0) {                 // wave-private slot: no race
                    sm_s[w][s * 16 + col16] += ps;
                    sm_q[w][s * 16 + col16] += pq;
                }
            }
        } else {
            const int fbase = (T0 + i) * 64 + mr + kg * 4;
            #pragma unroll
            for (int s = 0; s < 4; ++s) {
                const int o = oh + s * 16 + col16;
                const float sc = ss[o];
                const float sh = ss[O_DIM + o];
                f32x4 v = acc[s];
                v.x = fmaxf(fmaf(v.x, sc, sh), 0.f);
                v.y = fmaxf(fmaf(v.y, sc, sh), 0.f);
                v.z = fmaxf(fmaf(v.z, sc, sh), 0.f);
                v.w = fmaxf(fmaf(v.w, sc, sh), 0.f);
                __builtin_nontemporal_store(v, (f32x4*)(y + ((size_t)b * O_DIM + o) * F_DIM + fbase));
            }
        }

        // write next tile into the other buffer (gathers die here)
        if (i < ITERS - 1) {
            char* Arow = A2[cur ^ 1] + p * 256;
            *(uint4*)(Arow + ((sub * 16) ^ swp)) = g0;
            *(uint4*)(Arow + ((128 + sub * 16) ^ swp)) =
                make_uint4(beta_pair(g0.x, g1.x, g2.x, g3.x),
                           beta_pair(g0.y, g1.y, g2.y, g3.y),
                           beta_pair(g0.z, g1.z, g2.z, g3.z),
                           beta_pair(g0.w, g1.w, g2.w, g3.w));
        }
        __syncthreads();
    }

    if (MODE == 0) {
        if (t < 128) {
            const int half = t >> 6, oo = t & 63;
            float a = 0.f, c = 0.f;
            #pragma unroll
            for (int q = 0; q < 4; ++q) {
                a += sm_s[half * 4 + q][oo];
                c += sm_q[half * 4 + q][oo];
            }
            part[(size_t)t * PBLK + bid]         = a;
            part[(size_t)(128 + t) * PBLK + bid] = c;
        }
    }
}

// ------------- Pass 3: reduce partials + finalize scale/shift ---------------
__global__ __launch_bounds__(256) void k_reduce_finalize(const float* __restrict__ part,
                                                         const float* __restrict__ gamma,
                                                         const float* __restrict__ beta_bn,
                                                         float* __restrict__ ss) {
    const int o = blockIdx.x;
    const int t = threadIdx.x;
    const float4* p1 = (const float4*)(part + (size_t)o * PBLK);
    const float4* p2 = (const float4*)(part + (size_t)(128 + o) * PBLK);
    float s = 0.f, q = 0.f;
    for (int i = t; i < PBLK / 4; i += 256) {
        const float4 v = p1[i];
        s += v.x + v.y + v.z + v.w;
        const float4 u = p2[i];
        q += u.x + u.y + u.z + u.w;
    }
    #pragma unroll
    for (int off = 32; off > 0; off >>= 1) {
        s += __shfl_down(s, off, 64);
        q += __shfl_down(q, off, 64);
    }
    __shared__ float ls[8];
    const int wid = t >> 6, lane = t & 63;
    if (lane == 0) { ls[wid] = s; ls[4 + wid] = q; }
    __syncthreads();
    if (t == 0) {
        const float ts = ls[0] + ls[1] + ls[2] + ls[3];
        const float tq = ls[4] + ls[5] + ls[6] + ls[7];
        const float n    = (float)B_DIM * (float)F_DIM;
        const float mean = ts / n;
        const float var  = tq / n - mean * mean;
        const float sc   = gamma[o] * rsqrtf(var + 1e-5f);
        ss[o]         = sc;
        ss[O_DIM + o] = beta_bn[o] - mean * sc;
    }
}

// ================== fallback path (small ws) — round-1 known-correct ========
__global__ __launch_bounds__(256) void k_compute_slow(const float* __restrict__ xsrc,
                                                      const int*   __restrict__ adj,
                                                      const float* __restrict__ W,
                                                      const float* __restrict__ bias,
                                                      float*       __restrict__ y) {
    const int b = blockIdx.y;
    const int f = blockIdx.x * 256 + threadIdx.x;
    const int4 a = ((const int4*)adj)[(size_t)b * F_DIM + f];
    float tg[64], bt[64];
    const float* base = xsrc + (size_t)b * C_DIM * F_DIM;
    #pragma unroll
    for (int c = 0; c < 64; ++c) {
        const float tv = base[(size_t)c * F_DIM + a.x];
        const float n1 = base[(size_t)c * F_DIM + a.y];
        const float n2 = base[(size_t)c * F_DIM + a.z];
        const float n3 = base[(size_t)c * F_DIM + a.w];
        tg[c] = tv;
        bt[c] = fabsf(tv - n1) + fabsf(tv - n2) + fabsf(tv - n3);
    }
    float* yb = y + (size_t)b * O_DIM * F_DIM + f;
    const float2* W2 = (const float2*)W;
    #pragma unroll 4
    for (int o = 0; o < O_DIM; ++o) {
        float acc = bias[o];
        #pragma unroll
        for (int c = 0; c < 64; ++c) {
            const float2 wv = W2[o * 64 + c];
            acc = fmaf(tg[c], wv.x, fmaf(bt[c], wv.y, acc));
        }
        yb[(size_t)o * F_DIM] = acc;
    }
}

__global__ __launch_bounds__(256) void k_stats(const float* __restrict__ y,
                                               float* __restrict__ stats) {
    const int o = blockIdx.x;
    const int b = blockIdx.y;
    const float4* row = (const float4*)(y + ((size_t)b * O_DIM + o) * F_DIM);
    float s = 0.f, s2 = 0.f;
    for (int i = threadIdx.x; i < F_DIM / 4; i += 256) {
        const float4 v = row[i];
        s  += v.x + v.y + v.z + v.w;
        s2 += v.x * v.x + v.y * v.y + v.z * v.z + v.w * v.w;
    }
    #pragma unroll
    for (int off = 32; off > 0; off >>= 1) {
        s  += __shfl_down(s,  off, 64);
        s2 += __shfl_down(s2, off, 64);
    }
    __shared__ float ls[4], ls2[4];
    const int wid = threadIdx.x >> 6, lane = threadIdx.x & 63;
    if (lane == 0) { ls[wid] = s; ls2[wid] = s2; }
    __syncthreads();
    if (threadIdx.x == 0) {
        atomicAdd(&stats[o],         ls[0] + ls[1] + ls[2] + ls[3]);
        atomicAdd(&stats[O_DIM + o], ls2[0] + ls2[1] + ls2[2] + ls2[3]);
    }
}

__global__ void k_finalize(const float* __restrict__ stats,
                           const float* __restrict__ gamma,
                           const float* __restrict__ beta_bn,
                           float* __restrict__ ss) {
    const int o = threadIdx.x;
    if (o < O_DIM) {
        const float n    = (float)B_DIM * (float)F_DIM;
        const float mean = stats[o] / n;
        const float var  = stats[O_DIM + o] / n - mean * mean;
        const float sc   = gamma[o] * rsqrtf(var + 1e-5f);
        ss[o]         = sc;
        ss[O_DIM + o] = beta_bn[o] - mean * sc;
    }
}

__global__ __launch_bounds__(256) void k_norm(float* __restrict__ y,
                                              const float* __restrict__ ss) {
    const size_t n4 = (size_t)B_DIM * O_DIM * F_DIM / 4;
    const size_t stride = (size_t)gridDim.x * blockDim.x;
    float4* y4 = (float4*)y;
    for (size_t i = (size_t)blockIdx.x * blockDim.x + threadIdx.x; i < n4; i += stride) {
        const int o = (int)((i >> 12) & (O_DIM - 1));
        const float sc = ss[o];
        const float sh = ss[O_DIM + o];
        float4 v = y4[i];
        v.x = fmaxf(fmaf(v.x, sc, sh), 0.f);
        v.y = fmaxf(fmaf(v.y, sc, sh), 0.f);
        v.z = fmaxf(fmaf(v.z, sc, sh), 0.f);
        v.w = fmaxf(fmaf(v.w, sc, sh), 0.f);
        y4[i] = v;
    }
}

extern "C" void kernel_launch(void* const* d_in, const int* in_sizes, int n_in,
                              void* d_out, int out_size, void* d_ws, size_t ws_size,
                              hipStream_t stream) {
    const float* x       = (const float*)d_in[0];
    const int*   adj     = (const int*)  d_in[1];
    const float* W       = (const float*)d_in[2];
    const float* bias    = (const float*)d_in[3];
    const float* gamma   = (const float*)d_in[4];
    const float* beta_bn = (const float*)d_in[5];
    float* out = (float*)d_out;

    const size_t XT_B   = (size_t)B_DIM * F_DIM * C_DIM * 2;            // 64 MB
    const size_t PART_B = (size_t)2 * O_DIM * PBLK * sizeof(float);     // 512 KB

    float*  stats = (float*)d_ws;
    float*  ss    = (float*)((char*)d_ws + 1024);
    ushort* Wtg   = (ushort*)((char*)d_ws + 4096);
    ushort* xt    = (ushort*)((char*)d_ws + 65536);
    float*  part  = (float*)((char*)d_ws + 65536 + XT_B);

    const size_t need = 65536 + XT_B + PART_B;

    if (ws_size >= need) {
        k_transpose<<<dim3(F_DIM / 64, B_DIM), 256, 0, stream>>>(x, xt, W, Wtg);
        k_pipe<0><<<dim3(PBLK), 512, 0, stream>>>(xt, adj, Wtg, bias, nullptr, nullptr, part);
        k_reduce_finalize<<<O_DIM, 256, 0, stream>>>(part, gamma, beta_bn, ss);
        k_pipe<1><<<dim3(PBLK), 512, 0, stream>>>(xt, adj, Wtg, bias, ss, out, nullptr);
    } else {
        hipMemsetAsync(stats, 0, 2 * O_DIM * sizeof(float), stream);
        k_compute_slow<<<dim3(F_DIM / 256, B_DIM), 256, 0, stream>>>(x, adj, W, bias, out);
        k_stats<<<dim3(O_DIM, B_DIM), 256, 0, stream>>>(out, stats);
        k_finalize<<<1, 128, 0, stream>>>(stats, gamma, beta_bn, ss);
        k_norm<<<2048, 256, 0, stream>>>(out, ss);
    }
}

// Round 15
// 174.996 us; speedup vs baseline: 2.0357x; 1.1481x over previous
//
#include <hip/hip_runtime.h>

#define B_DIM 32
#define C_DIM 64
#define F_DIM 16384
#define O_DIM 128
#define NBLK4 ((F_DIM / 128) * B_DIM)   // 4096 compute blocks (128 points each)

typedef __attribute__((ext_vector_type(8))) short short8;
typedef __attribute__((ext_vector_type(4))) float f32x4;

__device__ __forceinline__ ushort f2bf(float f) {
    union { float f; uint u; } v; v.f = f;
    return (ushort)((v.u + 0x7FFFu + ((v.u >> 16) & 1u)) >> 16);
}
__device__ __forceinline__ float bflo(uint u) {
    union { uint u; float f; } v; v.u = u << 16; return v.f;
}
__device__ __forceinline__ float bfhi(uint u) {
    union { uint u; float f; } v; v.u = u & 0xFFFF0000u; return v.f;
}
__device__ __forceinline__ uint beta_pair(uint tu, uint au, uint bu, uint cu) {
    const float tl = bflo(tu), th = bfhi(tu);
    const float lo = fabsf(tl - bflo(au)) + fabsf(tl - bflo(bu)) + fabsf(tl - bflo(cu));
    const float hi = fabsf(th - bfhi(au)) + fabsf(th - bfhi(bu)) + fabsf(th - bfhi(cu));
    return (uint)f2bf(lo) | ((uint)f2bf(hi) << 16);
}

// ------- Pass 1: transpose x (B,C,F) fp32 -> xt (B,F,C) bf16  (+W prep) -----
__global__ __launch_bounds__(256) void k_transpose(const float* __restrict__ x,
                                                   ushort* __restrict__ xt,
                                                   const float* __restrict__ W,
                                                   ushort* __restrict__ Wtg) {
    __shared__ float tile[64][65];
    const int b  = blockIdx.y;
    const int f0 = blockIdx.x * 64;
    const int t  = threadIdx.x;
    const int fl = t & 63;
    const int q  = t >> 6;

    const float* xb = x + (size_t)b * C_DIM * F_DIM;
    #pragma unroll
    for (int i = 0; i < 16; ++i) {
        const int c = q + i * 4;
        tile[c][fl] = __builtin_nontemporal_load(&xb[(size_t)c * F_DIM + f0 + fl]);
    }

    if (blockIdx.x == 0 && blockIdx.y == 0 && t < 128) {
        const int o = t;
        #pragma unroll 8
        for (int c = 0; c < C_DIM; ++c) {
            Wtg[o * 128 + c]      = f2bf(W[o * 128 + c * 2]);
            Wtg[o * 128 + 64 + c] = f2bf(W[o * 128 + c * 2 + 1]);
        }
    }

    __syncthreads();

    const int f  = t >> 2;
    const int ch = t & 3;
    union { ushort s[16]; uint4 v[2]; } u;
    #pragma unroll
    for (int j = 0; j < 16; ++j)
        u.s[j] = f2bf(tile[ch * 16 + j][f]);
    ushort* dst = xt + ((size_t)b * F_DIM + f0 + f) * C_DIM + ch * 16;
    *(uint4*)(dst)     = u.v[0];
    *(uint4*)(dst + 8) = u.v[1];
}

// ------------- Pass 2/4: gather + beta + MFMA GEMM (round-11 proven) --------
// 512 threads / 8 waves / 128-point A tile; Wsm staged in LDS; 1 barrier.
// MODE 0: accumulate per-block (sum,sumsq) per o -> part, no y store.
// MODE 1: apply scale/shift (ss) + ReLU, store final y (nontemporal).
template <int MODE>
__global__ __launch_bounds__(512, 4) void k_compute_t(const ushort* __restrict__ xt,
                                                      const int*    __restrict__ adj,
                                                      const ushort* __restrict__ Wtg,
                                                      const float*  __restrict__ bias,
                                                      const float*  __restrict__ ss,
                                                      float*        __restrict__ y,
                                                      float*        __restrict__ part) {
    __shared__ __align__(16) char Asm[128 * 256];   // A tile: 128 rows x 128 bf16 (swizzled)
    __shared__ __align__(16) char Wsm[128 * 256];   // Wt:    128 rows x 128 bf16 (swizzled)

    const int bid = blockIdx.x;
    const int tg  = (bid & 7) * (NBLK4 / 8) + (bid >> 3);   // XCD-aware, bijective
    const int b   = tg >> 7;                                 // 128 tiles per batch
    const int f0  = (tg & 127) * 128;
    const int t   = threadIdx.x;

    // --- issue all 8 scattered gather loads FIRST (latency overlap) ---
    const int p  = t >> 2;          // point 0..127
    const int ch = t & 3;           // 32B c-chunk
    const int4 a4 = ((const int4*)adj)[(size_t)b * F_DIM + f0 + p];
    const char* xb = (const char*)(xt + (size_t)b * F_DIM * C_DIM);
    const char* r0 = xb + (size_t)a4.x * 128 + ch * 32;
    const char* r1 = xb + (size_t)a4.y * 128 + ch * 32;
    const char* r2 = xb + (size_t)a4.z * 128 + ch * 32;
    const char* r3 = xb + (size_t)a4.w * 128 + ch * 32;
    uint4 g[8];
    g[0] = *(const uint4*)(r0);  g[1] = *(const uint4*)(r0 + 16);
    g[2] = *(const uint4*)(r1);  g[3] = *(const uint4*)(r1 + 16);
    g[4] = *(const uint4*)(r2);  g[5] = *(const uint4*)(r2 + 16);
    g[6] = *(const uint4*)(r3);  g[7] = *(const uint4*)(r3 + 16);

    // --- stage Wt into swizzled LDS (512 threads x 4 x 16B = 32 KB) ---
    {
        const uint4* src = (const uint4*)Wtg;
        #pragma unroll
        for (int jj = 0; jj < 4; ++jj) {
            const int fb    = t * 64 + jj * 16;
            const int o     = fb >> 8;
            const int inner = fb & 255;
            *(uint4*)(Wsm + (o << 8) + (inner ^ ((o & 7) << 4))) = src[fb >> 4];
        }
    }

    // --- beta + A-tile store (swizzled) ---
    {
        const int sw = (p & 7) << 4;
        char* Arow = Asm + p * 256;
        #pragma unroll
        for (int h = 0; h < 2; ++h) {
            const uint4 t0 = g[h], n1 = g[2 + h], n2 = g[4 + h], n3 = g[6 + h];
            *(uint4*)(Arow + ((ch * 32 + h * 16) ^ sw)) = t0;   // target bits
            const uint tu[4] = { t0.x, t0.y, t0.z, t0.w };
            const uint au[4] = { n1.x, n1.y, n1.z, n1.w };
            const uint bu[4] = { n2.x, n2.y, n2.z, n2.w };
            const uint cu[4] = { n3.x, n3.y, n3.z, n3.w };
            uint bt[4];
            #pragma unroll
            for (int qq = 0; qq < 4; ++qq)
                bt[qq] = beta_pair(tu[qq], au[qq], bu[qq], cu[qq]);
            *(uint4*)(Arow + ((128 + ch * 32 + h * 16) ^ sw)) =
                make_uint4(bt[0], bt[1], bt[2], bt[3]);
        }
    }

    __syncthreads();

    // --- MFMA: wave w (0..7) owns m-rows [w*16, w*16+16), all 128 o ---
    const int w     = t >> 6;
    const int l     = t & 63;
    const int col16 = l & 15;
    const int kg    = l >> 4;
    const int swl   = (l & 7) << 4;

    f32x4 acc[8];
    #pragma unroll
    for (int s = 0; s < 8; ++s) {
        const float bv = bias[s * 16 + col16];
        acc[s] = (f32x4){ bv, bv, bv, bv };
    }

    const char* ArowR = Asm + (w * 16 + col16) * 256;
    #pragma unroll
    for (int kk = 0; kk < 4; ++kk) {
        const int koff = kk * 64 + kg * 16;
        const short8 af = *(const short8*)(ArowR + (koff ^ swl));
        #pragma unroll
        for (int s = 0; s < 8; ++s) {
            const short8 bf = *(const short8*)(Wsm + (s * 16 + col16) * 256 + (koff ^ swl));
            acc[s] = __builtin_amdgcn_mfma_f32_16x16x32_bf16(af, bf, acc[s], 0, 0, 0);
        }
    }

    if (MODE == 0) {
        // --- reduce acc -> per-block (sum,sumsq) per o, write partials ---
        __shared__ float sm_s[8][128];
        __shared__ float sm_q[8][128];
        #pragma unroll
        for (int s = 0; s < 8; ++s) {
            float ps = acc[s].x + acc[s].y + acc[s].z + acc[s].w;
            float pq = acc[s].x * acc[s].x + acc[s].y * acc[s].y
                     + acc[s].z * acc[s].z + acc[s].w * acc[s].w;
            ps += __shfl_xor(ps, 16, 64);  pq += __shfl_xor(pq, 16, 64);
            ps += __shfl_xor(ps, 32, 64);  pq += __shfl_xor(pq, 32, 64);
            if (kg == 0) {
                sm_s[w][s * 16 + col16] = ps;
                sm_q[w][s * 16 + col16] = pq;
            }
        }
        __syncthreads();
        if (t < 128) {
            float a = 0.f, c = 0.f;
            #pragma unroll
            for (int ww = 0; ww < 8; ++ww) { a += sm_s[ww][t]; c += sm_q[ww][t]; }
            part[(size_t)t * NBLK4 + bid]         = a;
            part[(size_t)(128 + t) * NBLK4 + bid] = c;
        }
    } else {
        // MODE 1: normalize + ReLU + coalesced nontemporal float4 stores
        const int fbase = f0 + w * 16 + kg * 4;
        #pragma unroll
        for (int s = 0; s < 8; ++s) {
            const int o = s * 16 + col16;
            const float sc = ss[o];
            const float sh = ss[O_DIM + o];
            f32x4 v = acc[s];
            v.x = fmaxf(fmaf(v.x, sc, sh), 0.f);
            v.y = fmaxf(fmaf(v.y, sc, sh), 0.f);
            v.z = fmaxf(fmaf(v.z, sc, sh), 0.f);
            v.w = fmaxf(fmaf(v.w, sc, sh), 0.f);
            __builtin_nontemporal_store(v, (f32x4*)(y + ((size_t)b * O_DIM + o) * F_DIM + fbase));
        }
    }
}

// ------------- Pass 3: reduce partials + finalize scale/shift ---------------
__global__ __launch_bounds__(256) void k_reduce_finalize(const float* __restrict__ part,
                                                         const float* __restrict__ gamma,
                                                         const float* __restrict__ beta_bn,
                                                         float* __restrict__ ss) {
    const int o = blockIdx.x;
    const int t = threadIdx.x;
    const float4* p1 = (const float4*)(part + (size_t)o * NBLK4);
    const float4* p2 = (const float4*)(part + (size_t)(128 + o) * NBLK4);
    float s = 0.f, q = 0.f;
    for (int i = t; i < NBLK4 / 4; i += 256) {
        const float4 v = p1[i];
        s += v.x + v.y + v.z + v.w;
        const float4 u = p2[i];
        q += u.x + u.y + u.z + u.w;
    }
    #pragma unroll
    for (int off = 32; off > 0; off >>= 1) {
        s += __shfl_down(s, off, 64);
        q += __shfl_down(q, off, 64);
    }
    __shared__ float ls[8];
    const int wid = t >> 6, lane = t & 63;
    if (lane == 0) { ls[wid] = s; ls[4 + wid] = q; }
    __syncthreads();
    if (t == 0) {
        const float ts = ls[0] + ls[1] + ls[2] + ls[3];
        const float tq = ls[4] + ls[5] + ls[6] + ls[7];
        const float n    = (float)B_DIM * (float)F_DIM;
        const float mean = ts / n;
        const float var  = tq / n - mean * mean;
        const float sc   = gamma[o] * rsqrtf(var + 1e-5f);
        ss[o]         = sc;
        ss[O_DIM + o] = beta_bn[o] - mean * sc;
    }
}

// ================== fallback path (small ws) — round-1 known-correct ========
__global__ __launch_bounds__(256) void k_compute_slow(const float* __restrict__ xsrc,
                                                      const int*   __restrict__ adj,
                                                      const float* __restrict__ W,
                                                      const float* __restrict__ bias,
                                                      float*       __restrict__ y) {
    const int b = blockIdx.y;
    const int f = blockIdx.x * 256 + threadIdx.x;
    const int4 a = ((const int4*)adj)[(size_t)b * F_DIM + f];
    float tg[64], bt[64];
    const float* base = xsrc + (size_t)b * C_DIM * F_DIM;
    #pragma unroll
    for (int c = 0; c < 64; ++c) {
        const float tv = base[(size_t)c * F_DIM + a.x];
        const float n1 = base[(size_t)c * F_DIM + a.y];
        const float n2 = base[(size_t)c * F_DIM + a.z];
        const float n3 = base[(size_t)c * F_DIM + a.w];
        tg[c] = tv;
        bt[c] = fabsf(tv - n1) + fabsf(tv - n2) + fabsf(tv - n3);
    }
    float* yb = y + (size_t)b * O_DIM * F_DIM + f;
    const float2* W2 = (const float2*)W;
    #pragma unroll 4
    for (int o = 0; o < O_DIM; ++o) {
        float acc = bias[o];
        #pragma unroll
        for (int c = 0; c < 64; ++c) {
            const float2 wv = W2[o * 64 + c];
            acc = fmaf(tg[c], wv.x, fmaf(bt[c], wv.y, acc));
        }
        yb[(size_t)o * F_DIM] = acc;
    }
}

__global__ __launch_bounds__(256) void k_stats(const float* __restrict__ y,
                                               float* __restrict__ stats) {
    const int o = blockIdx.x;
    const int b = blockIdx.y;
    const float4* row = (const float4*)(y + ((size_t)b * O_DIM + o) * F_DIM);
    float s = 0.f, s2 = 0.f;
    for (int i = threadIdx.x; i < F_DIM / 4; i += 256) {
        const float4 v = row[i];
        s  += v.x + v.y + v.z + v.w;
        s2 += v.x * v.x + v.y * v.y + v.z * v.z + v.w * v.w;
    }
    #pragma unroll
    for (int off = 32; off > 0; off >>= 1) {
        s  += __shfl_down(s,  off, 64);
        s2 += __shfl_down(s2, off, 64);
    }
    __shared__ float ls[4], ls2[4];
    const int wid = threadIdx.x >> 6, lane = threadIdx.x & 63;
    if (lane == 0) { ls[wid] = s; ls2[wid] = s2; }
    __syncthreads();
    if (threadIdx.x == 0) {
        atomicAdd(&stats[o],         ls[0] + ls[1] + ls[2] + ls[3]);
        atomicAdd(&stats[O_DIM + o], ls2[0] + ls2[1] + ls2[2] + ls2[3]);
    }
}

__global__ void k_finalize(const float* __restrict__ stats,
                           const float* __restrict__ gamma,
                           const float* __restrict__ beta_bn,
                           float* __restrict__ ss) {
    const int o = threadIdx.x;
    if (o < O_DIM) {
        const float n    = (float)B_DIM * (float)F_DIM;
        const float mean = stats[o] / n;
        const float var  = stats[O_DIM + o] / n - mean * mean;
        const float sc   = gamma[o] * rsqrtf(var + 1e-5f);
        ss[o]         = sc;
        ss[O_DIM + o] = beta_bn[o] - mean * sc;
    }
}

__global__ __launch_bounds__(256) void k_norm(float* __restrict__ y,
                                              const float* __restrict__ ss) {
    const size_t n4 = (size_t)B_DIM * O_DIM * F_DIM / 4;
    const size_t stride = (size_t)gridDim.x * blockDim.x;
    float4* y4 = (float4*)y;
    for (size_t i = (size_t)blockIdx.x * blockDim.x + threadIdx.x; i < n4; i += stride) {
        const int o = (int)((i >> 12) & (O_DIM - 1));
        const float sc = ss[o];
        const float sh = ss[O_DIM + o];
        float4 v = y4[i];
        v.x = fmaxf(fmaf(v.x, sc, sh), 0.f);
        v.y = fmaxf(fmaf(v.y, sc, sh), 0.f);
        v.z = fmaxf(fmaf(v.z, sc, sh), 0.f);
        v.w = fmaxf(fmaf(v.w, sc, sh), 0.f);
        y4[i] = v;
    }
}

extern "C" void kernel_launch(void* const* d_in, const int* in_sizes, int n_in,
                              void* d_out, int out_size, void* d_ws, size_t ws_size,
                              hipStream_t stream) {
    const float* x       = (const float*)d_in[0];
    const int*   adj     = (const int*)  d_in[1];
    const float* W       = (const float*)d_in[2];
    const float* bias    = (const float*)d_in[3];
    const float* gamma   = (const float*)d_in[4];
    const float* beta_bn = (const float*)d_in[5];
    float* out = (float*)d_out;

    const size_t XT_B   = (size_t)B_DIM * F_DIM * C_DIM * 2;            // 64 MB
    const size_t PART_B = (size_t)2 * O_DIM * NBLK4 * sizeof(float);    // 4 MB

    float*  stats = (float*)d_ws;
    float*  ss    = (float*)((char*)d_ws + 1024);
    ushort* Wtg   = (ushort*)((char*)d_ws + 4096);
    ushort* xt    = (ushort*)((char*)d_ws + 65536);
    float*  part  = (float*)((char*)d_ws + 65536 + XT_B);

    const size_t need = 65536 + XT_B + PART_B;

    if (ws_size >= need) {
        k_transpose<<<dim3(F_DIM / 64, B_DIM), 256, 0, stream>>>(x, xt, W, Wtg);
        k_compute_t<0><<<dim3(NBLK4), 512, 0, stream>>>(xt, adj, Wtg, bias, nullptr, nullptr, part);
        k_reduce_finalize<<<O_DIM, 256, 0, stream>>>(part, gamma, beta_bn, ss);
        k_compute_t<1><<<dim3(NBLK4), 512, 0, stream>>>(xt, adj, Wtg, bias, ss, out, nullptr);
    } else {
        hipMemsetAsync(stats, 0, 2 * O_DIM * sizeof(float), stream);
        k_compute_slow<<<dim3(F_DIM / 256, B_DIM), 256, 0, stream>>>(x, adj, W, bias, out);
        k_stats<<<dim3(O_DIM, B_DIM), 256, 0, stream>>>(out, stats);
        k_finalize<<<1, 128, 0, stream>>>(stats, gamma, beta_bn, ss);
        k_norm<<<2048, 256, 0, stream>>>(out, ss);
    }
}